// Round 3
// baseline (458.640 us; speedup 1.0000x reference)
//
#include <hip/hip_runtime.h>
#include <hip/hip_bf16.h>
#include <cstdint>
#include <cstddef>

// Problem constants (B,N,M,C2,C1) = (4, 8192, 2048, 256, 128)
static constexpr int BB   = 4;
static constexpr int NN   = 8192;
static constexpr int MM   = 2048;
static constexpr int C1   = 128;
static constexpr int C2   = 256;
static constexpr int CH0  = C2 + C1;   // 384  (K of GEMM0)
static constexpr int O0   = 256;       // out channels layer 0
static constexpr int O1   = 128;       // out channels layer 1
static constexpr int NCOL = BB * NN;   // 32768 columns
static constexpr float BN_EPS = 1e-5f;

using u16 = unsigned short;
typedef __attribute__((ext_vector_type(8))) short short8;
typedef __attribute__((ext_vector_type(4))) float f32x4;

static __device__ __forceinline__ float bf2f(u16 u) {
    union { unsigned int i; float f; } v; v.i = ((unsigned int)u) << 16; return v.f;
}
static __device__ __forceinline__ u16 f2bf(float f) {
    union { float f; unsigned int i; } v; v.f = f;
    unsigned int r = (v.i + 0x7fffu + ((v.i >> 16) & 1u)) >> 16;
    return (u16)r;
}

// ---------------------------------------------------------------------------
// K0: zero the BN stats accumulators (ws is poisoned 0xAA before every call)
__global__ void zero_stats_kernel(float* s0, float* s1) {
    int t = threadIdx.x;
    if (t < 2 * O0) s0[t] = 0.f;
    if (t < 2 * O1) s1[t] = 0.f;
}

// ---------------------------------------------------------------------------
// K1: f32 -> bf16 batched transpose  in[b][R][C] (f32) -> out[b][C][R] (bf16)
__global__ __launch_bounds__(256) void transpose_f32_bf16(const float* __restrict__ in,
                                                          u16* __restrict__ out,
                                                          int R, int C) {
    __shared__ float tile[32][33];
    int b  = blockIdx.z;
    int c0 = blockIdx.x * 32;
    int r0 = blockIdx.y * 32;
    const float* pin = in  + (size_t)b * R * C;
    u16*        pout = out + (size_t)b * R * C;
    int tx = threadIdx.x, ty = threadIdx.y;   // block (32,8)
#pragma unroll
    for (int j = 0; j < 4; ++j) {
        int r = ty + j * 8;
        tile[r][tx] = pin[(size_t)(r0 + r) * C + (c0 + tx)];
    }
    __syncthreads();
#pragma unroll
    for (int j = 0; j < 4; ++j) {
        int c = ty + j * 8;
        pout[(size_t)(c0 + c) * R + (r0 + tx)] = f2bf(tile[tx][c]);
    }
}

// ---------------------------------------------------------------------------
// K2: 3-NN + combined (distance * normal) interpolation weights. f32 inputs.
// One thread per query point; xyz2 staged in LDS as (x,y,z,|p|^2).
// Distance formula replicates the reference order: (qq + pp) - 2*qp,
// fp contract off so we match numpy's non-FMA f32 evaluation (tie fidelity).
__global__ __launch_bounds__(128) void three_nn_kernel(const float* __restrict__ xyz1,
                                                       const float* __restrict__ xyz2,
                                                       const float* __restrict__ norm1,
                                                       const float* __restrict__ norm2,
                                                       int* __restrict__ idxOut,
                                                       float* __restrict__ wOut) {
#pragma clang fp contract(off)
    __shared__ float4 pts[MM];
    int b    = blockIdx.x >> 6;          // 64 blocks of 128 queries per batch
    int nblk = blockIdx.x & 63;
    int t    = threadIdx.x;

    const float* x2 = xyz2 + (size_t)b * 3 * MM;
    for (int i = t; i < MM; i += 128) {
        float px = x2[i];
        float py = x2[MM + i];
        float pz = x2[2 * MM + i];
        float pp = (px * px + py * py) + pz * pz;
        pts[i] = make_float4(px, py, pz, pp);
    }
    __syncthreads();

    int n = nblk * 128 + t;
    const float* x1 = xyz1 + (size_t)b * 3 * NN;
    float qx = x1[n], qy = x1[NN + n], qz = x1[2 * NN + n];
    float qq = (qx * qx + qy * qy) + qz * qz;

    float d0 = 3.4e38f, d1 = 3.4e38f, d2v = 3.4e38f;
    int   i0 = 0, i1 = 0, i2 = 0;
#pragma unroll 4
    for (int m = 0; m < MM; ++m) {
        float4 P = pts[m];
        float qp = (qx * P.x + qy * P.y) + qz * P.z;
        float d  = (qq + P.w) - 2.0f * qp;
        if (d < d2v) {
            if (d < d1) {
                if (d < d0) { d2v = d1; i2 = i1; d1 = d0; i1 = i0; d0 = d; i0 = m; }
                else        { d2v = d1; i2 = i1; d1 = d;  i1 = m; }
            } else          { d2v = d;  i2 = m; }
        }
    }

    // distance weights
    float s0 = sqrtf(fmaxf(d0, 1e-20f));
    float s1 = sqrtf(fmaxf(d1, 1e-20f));
    float s2 = sqrtf(fmaxf(d2v, 1e-20f));
    float r0 = 1.0f / fmaxf(s0, 1e-10f);
    float r1 = 1.0f / fmaxf(s1, 1e-10f);
    float r2 = 1.0f / fmaxf(s2, 1e-10f);
    float rs = (r0 + r1) + r2;
    float w0 = r0 / rs, w1 = r1 / rs, w2 = r2 / rs;

    // normal-space weights
    const float* nm1 = norm1 + (size_t)b * 3 * NN;
    const float* nm2 = norm2 + (size_t)b * 3 * MM;
    float ax = nm1[n], ay = nm1[NN + n], az = nm1[2 * NN + n];
    float nd[3]; int ii[3] = {i0, i1, i2};
#pragma unroll
    for (int k = 0; k < 3; ++k) {
        int ik = ii[k];
        float dx = ax - nm2[ik];
        float dy = ay - nm2[MM + ik];
        float dz = az - nm2[2 * MM + ik];
        nd[k] = sqrtf((dx * dx + dy * dy) + dz * dz);
    }
    float m0 = 1.0f / fmaxf(nd[0], 1e-10f);
    float m1 = 1.0f / fmaxf(nd[1], 1e-10f);
    float m2 = 1.0f / fmaxf(nd[2], 1e-10f);
    float ms = (m0 + m1) + m2;

    int col = b * NN + n;
    idxOut[col * 3 + 0] = i0;
    idxOut[col * 3 + 1] = i1;
    idxOut[col * 3 + 2] = i2;
    wOut[col * 3 + 0] = w0 * (m0 / ms);
    wOut[col * 3 + 1] = w1 * (m1 / ms);
    wOut[col * 3 + 2] = w2 * (m2 / ms);
}

// ---------------------------------------------------------------------------
// K3: build x^T[col][k] (bf16, K-contiguous): k<256 = interpolated points2,
// k>=256 = copied points1 channels. 16 columns per 256-thread block.
__global__ __launch_bounds__(256) void build_xT_kernel(const int* __restrict__ idx,
                                                       const float* __restrict__ w,
                                                       const u16* __restrict__ p2T,
                                                       const u16* __restrict__ p1T,
                                                       u16* __restrict__ xT) {
    int t = threadIdx.x;
    int col0 = blockIdx.x * 16;
    for (int i = 0; i < 16; ++i) {
        int col = col0 + i;
        int b = col >> 13;          // col / 8192
        int n = col & (NN - 1);
        int i0 = idx[col * 3 + 0], i1 = idx[col * 3 + 1], i2 = idx[col * 3 + 2];
        float w0 = w[col * 3 + 0], w1 = w[col * 3 + 1], w2 = w[col * 3 + 2];
        const u16* base = p2T + (size_t)b * MM * C2;
        float v = w0 * bf2f(base[(size_t)i0 * C2 + t])
                + w1 * bf2f(base[(size_t)i1 * C2 + t])
                + w2 * bf2f(base[(size_t)i2 * C2 + t]);
        xT[(size_t)col * CH0 + t] = f2bf(v);
        if (t < C1) {
            xT[(size_t)col * CH0 + C2 + t] = p1T[((size_t)b * NN + n) * C1 + t];
        }
    }
}

// ---------------------------------------------------------------------------
// K4/K6: GEMM  C^T[col][m] = sum_k A[m][k] * Bt[col][k] + bias[m]
// 128x128 tile, BK=64, 256 threads (4 waves, 2x2 of 64x64), 16x16x32 bf16 MFMA.
// Also accumulates per-channel sum / sumsq (training-mode BN stats) via atomics.
// FUSE: apply z = relu(v*scaleB[k]+shiftB[k]) to B elements while staging.
template <int KDIM, int LDC, bool FUSE>
__global__ __launch_bounds__(256) void gemm_bt_kernel(const u16* __restrict__ A,
                                                      const u16* __restrict__ Bt,
                                                      u16* __restrict__ Ct,
                                                      const float* __restrict__ bias,
                                                      const float* __restrict__ scaleB,
                                                      const float* __restrict__ shiftB,
                                                      float* __restrict__ stats,
                                                      int Mtot) {
    __shared__ u16 As[128][72];   // [m][k]  pad 64->72 (+16B; row stride 144B = 9*16)
    __shared__ u16 Bs[128][72];   // [col][k]
    int t   = threadIdx.x;
    int mb0 = blockIdx.y * 128;
    int cb0 = blockIdx.x * 128;
    int l   = t & 63;
    int wv  = t >> 6;
    int lm  = l & 15;
    int q   = l >> 4;
    int wm0 = (wv & 1) * 64;
    int wn0 = (wv >> 1) * 64;

    f32x4 acc[4][4] = {};

    for (int k0 = 0; k0 < KDIM; k0 += 64) {
        // Stage full 128x64 bf16 tiles: 1024 chunks of 16B each, 256 threads x 4.
#pragma unroll
        for (int j = 0; j < 4; ++j) {
            int chunk = t + j * 256;      // 0..1023
            int row = chunk >> 3;         // 0..127
            int kc  = (chunk & 7) * 8;    // 0,8,...,56
            uint4 va = *(const uint4*)(A + (size_t)(mb0 + row) * KDIM + k0 + kc);
            *(uint4*)&As[row][kc] = va;
            uint4 vb = *(const uint4*)(Bt + (size_t)(cb0 + row) * KDIM + k0 + kc);
            if (FUSE) {
                union { uint4 v; u16 u[8]; } uu; uu.v = vb;
#pragma unroll
                for (int e = 0; e < 8; ++e) {
                    int kch = k0 + kc + e;
                    float f = bf2f(uu.u[e]);
                    f = fmaxf(f * scaleB[kch] + shiftB[kch], 0.f);
                    uu.u[e] = f2bf(f);
                }
                vb = uu.v;
            }
            *(uint4*)&Bs[row][kc] = vb;
        }
        __syncthreads();
#pragma unroll
        for (int ks = 0; ks < 2; ++ks) {
            short8 av[4], bv[4];
#pragma unroll
            for (int mi = 0; mi < 4; ++mi)
                av[mi] = *(const short8*)&As[wm0 + mi * 16 + lm][ks * 32 + q * 8];
#pragma unroll
            for (int ni = 0; ni < 4; ++ni)
                bv[ni] = *(const short8*)&Bs[wn0 + ni * 16 + lm][ks * 32 + q * 8];
#pragma unroll
            for (int mi = 0; mi < 4; ++mi)
#pragma unroll
                for (int ni = 0; ni < 4; ++ni)
                    acc[mi][ni] = __builtin_amdgcn_mfma_f32_16x16x32_bf16(
                        av[mi], bv[ni], acc[mi][ni], 0, 0, 0);
        }
        __syncthreads();
    }

    // Epilogue: bias add, bf16 store (C layout: col=lane&15, row=q*4+r), BN stats.
#pragma unroll
    for (int mi = 0; mi < 4; ++mi) {
        int mg = mb0 + wm0 + mi * 16 + q * 4;   // global row (channel), 4 consecutive
        float bv4[4];
#pragma unroll
        for (int r = 0; r < 4; ++r) bv4[r] = bias[mg + r];
        float s[4]  = {0.f, 0.f, 0.f, 0.f};
        float s2[4] = {0.f, 0.f, 0.f, 0.f};
#pragma unroll
        for (int ni = 0; ni < 4; ++ni) {
            int col = cb0 + wn0 + ni * 16 + lm;
            union { u16 u[4]; uint2 d; } pk;
#pragma unroll
            for (int r = 0; r < 4; ++r) {
                float v = acc[mi][ni][r] + bv4[r];
                s[r]  += v;
                s2[r] += v * v;
                pk.u[r] = f2bf(v);
            }
            *(uint2*)(Ct + (size_t)col * LDC + mg) = pk.d;
        }
#pragma unroll
        for (int r = 0; r < 4; ++r) {
            float a = s[r], b2 = s2[r];
#pragma unroll
            for (int off = 1; off < 16; off <<= 1) {
                a  += __shfl_xor(a, off, 64);
                b2 += __shfl_xor(b2, off, 64);
            }
            if (lm == 0) {
                atomicAdd(&stats[mg + r], a);
                atomicAdd(&stats[Mtot + mg + r], b2);
            }
        }
    }
}

// ---------------------------------------------------------------------------
// K5/K7: fold BN stats into scale/shift:  z = y*scale[c] + shift[c]
__global__ void bn_params_kernel(const float* __restrict__ stats,
                                 const float* __restrict__ g,
                                 const float* __restrict__ be,
                                 float* __restrict__ scale,
                                 float* __restrict__ shift,
                                 int Mtot, float invN) {
    int c = threadIdx.x;
    if (c < Mtot) {
        float mean = stats[c] * invN;
        float var  = fmaxf(stats[Mtot + c] * invN - mean * mean, 0.f);
        float inv  = rsqrtf(var + BN_EPS);
        float sc   = g[c] * inv;
        scale[c] = sc;
        shift[c] = be[c] - mean * sc;
    }
}

// ---------------------------------------------------------------------------
// K8: final BN+ReLU on y1^T[col][c] (bf16) and transpose to out[b][c][n] (f32).
__global__ __launch_bounds__(256) void finalize_kernel(const u16* __restrict__ y1T,
                                                       const float* __restrict__ scale,
                                                       const float* __restrict__ shift,
                                                       float* __restrict__ out) {
    __shared__ float tile[64][129];
    int t  = threadIdx.x;
    int b  = blockIdx.y;
    int n0 = blockIdx.x * 64;
#pragma unroll
    for (int it = 0; it < 32; ++it) {
        int flat = it * 256 + t;
        int cl = flat >> 7;          // local col 0..63
        int c  = flat & 127;
        int col = b * NN + n0 + cl;
        float v = bf2f(y1T[(size_t)col * O1 + c]);
        tile[cl][c] = fmaxf(v * scale[c] + shift[c], 0.f);
    }
    __syncthreads();
#pragma unroll
    for (int it = 0; it < 32; ++it) {
        int flat = it * 256 + t;
        int c  = flat >> 6;          // channel 0..127
        int nl = flat & 63;
        out[(size_t)b * O1 * NN + (size_t)c * NN + n0 + nl] = tile[nl][c];
    }
}

// ---------------------------------------------------------------------------
extern "C" void kernel_launch(void* const* d_in, const int* in_sizes, int n_in,
                              void* d_out, int out_size, void* d_ws, size_t ws_size,
                              hipStream_t stream) {
    (void)in_sizes; (void)n_in; (void)out_size; (void)ws_size;

    const float* xyz1    = (const float*)d_in[0];
    const float* xyz2    = (const float*)d_in[1];
    const float* norm1   = (const float*)d_in[2];
    const float* norm2   = (const float*)d_in[3];
    const float* points1 = (const float*)d_in[4];
    const float* points2 = (const float*)d_in[5];
    const float* W0f     = (const float*)d_in[6];
    const float* b0      = (const float*)d_in[7];
    const float* g0      = (const float*)d_in[8];
    const float* be0     = (const float*)d_in[9];
    const float* W1f     = (const float*)d_in[10];
    const float* b1      = (const float*)d_in[11];
    const float* g1      = (const float*)d_in[12];
    const float* be1     = (const float*)d_in[13];
    float* out = (float*)d_out;

    // workspace carve-up (all 256B-aligned)
    char* w8 = (char*)d_ws;
    size_t off = 0;
    auto carve = [&](size_t bytes) { void* p = w8 + off; off += (bytes + 255) & ~(size_t)255; return p; };
    int*   idxW   = (int*)  carve((size_t)NCOL * 3 * sizeof(int));     // 393 KB
    float* wW     = (float*)carve((size_t)NCOL * 3 * sizeof(float));   // 393 KB
    u16*   p2T    = (u16*)  carve((size_t)BB * MM * C2 * 2);           // 2 MB
    u16*   p1T    = (u16*)  carve((size_t)BB * NN * C1 * 2);           // 8 MB
    u16*   W0b    = (u16*)  carve((size_t)O0 * CH0 * 2);               // 192 KB
    u16*   W1b    = (u16*)  carve((size_t)O1 * O0 * 2);                // 64 KB
    u16*   xT     = (u16*)  carve((size_t)NCOL * CH0 * 2);             // 25 MB
    u16*   y0T    = (u16*)  carve((size_t)NCOL * O0 * 2);              // 16 MB
    u16*   y1T    = (u16*)  carve((size_t)NCOL * O1 * 2);              // 8 MB
    float* stats0 = (float*)carve(2 * O0 * sizeof(float));
    float* stats1 = (float*)carve(2 * O1 * sizeof(float));
    float* scale0 = (float*)carve(O0 * sizeof(float));
    float* shift0 = (float*)carve(O0 * sizeof(float));
    float* scale1 = (float*)carve(O1 * sizeof(float));
    float* shift1 = (float*)carve(O1 * sizeof(float));

    const float invN = 1.0f / (float)NCOL;

    zero_stats_kernel<<<1, 512, 0, stream>>>(stats0, stats1);

    // f32 -> bf16 transposes (feature tensors) and weight conversions.
    transpose_f32_bf16<<<dim3(MM / 32, C2 / 32, BB), dim3(32, 8), 0, stream>>>(points2, p2T, C2, MM);
    transpose_f32_bf16<<<dim3(NN / 32, C1 / 32, BB), dim3(32, 8), 0, stream>>>(points1, p1T, C1, NN);
    // W0 (256x384) and W1 (128x256): row-major copies f32->bf16 via transpose of
    // transpose is overkill; reuse transpose kernel twice is wrong shape-wise, so
    // do it with a tiny dedicated grid: treat as [1][rows][cols] transpose to
    // [cols][rows] twice would transpose. Instead use a simple elementwise cast:
    {
        // elementwise f32->bf16 cast kernels (no layout change)
        struct Cast { };
    }
    // (launch below with lambda-style kernel)
    extern __global__ void cast_f32_bf16(const float*, u16*, int);
    cast_f32_bf16<<<(O0 * CH0 + 255) / 256, 256, 0, stream>>>(W0f, W0b, O0 * CH0);
    cast_f32_bf16<<<(O1 * O0 + 255) / 256, 256, 0, stream>>>(W1f, W1b, O1 * O0);

    three_nn_kernel<<<BB * (NN / 128), 128, 0, stream>>>(xyz1, xyz2, norm1, norm2, idxW, wW);

    build_xT_kernel<<<NCOL / 16, 256, 0, stream>>>(idxW, wW, p2T, p1T, xT);

    gemm_bt_kernel<CH0, O0, false><<<dim3(NCOL / 128, O0 / 128), 256, 0, stream>>>(
        W0b, xT, y0T, b0, nullptr, nullptr, stats0, O0);
    bn_params_kernel<<<1, O0, 0, stream>>>(stats0, g0, be0, scale0, shift0, O0, invN);

    gemm_bt_kernel<O0, O1, true><<<dim3(NCOL / 128, O1 / 128), 256, 0, stream>>>(
        W1b, y0T, y1T, b1, scale0, shift0, stats1, O1);
    bn_params_kernel<<<1, O1, 0, stream>>>(stats1, g1, be1, scale1, shift1, O1, invN);

    finalize_kernel<<<dim3(NN / 64, BB), 256, 0, stream>>>(y1T, scale1, shift1, out);
}

// elementwise f32 -> bf16 cast
__global__ __launch_bounds__(256) void cast_f32_bf16(const float* __restrict__ in,
                                                     u16* __restrict__ out, int n) {
    int i = blockIdx.x * 256 + threadIdx.x;
    if (i < n) out[i] = f2bf(in[i]);
}

// Round 4
// 333.854 us; speedup vs baseline: 1.3738x; 1.3738x over previous
//
#include <hip/hip_runtime.h>
#include <hip/hip_bf16.h>
#include <cstdint>
#include <cstddef>

// Problem constants (B,N,M,C2,C1) = (4, 8192, 2048, 256, 128)
static constexpr int BB   = 4;
static constexpr int NN   = 8192;
static constexpr int MM   = 2048;
static constexpr int C1   = 128;
static constexpr int C2   = 256;
static constexpr int CH0  = C2 + C1;   // 384  (K of GEMM0)
static constexpr int O0   = 256;       // out channels layer 0
static constexpr int O1   = 128;       // out channels layer 1
static constexpr int NCOL = BB * NN;   // 32768 columns
static constexpr float BN_EPS = 1e-5f;

using u16 = unsigned short;
typedef __attribute__((ext_vector_type(8))) short short8;
typedef __attribute__((ext_vector_type(4))) float f32x4;

static __device__ __forceinline__ float bf2f(u16 u) {
    union { unsigned int i; float f; } v; v.i = ((unsigned int)u) << 16; return v.f;
}
static __device__ __forceinline__ u16 f2bf(float f) {
    union { float f; unsigned int i; } v; v.f = f;
    unsigned int r = (v.i + 0x7fffu + ((v.i >> 16) & 1u)) >> 16;
    return (u16)r;
}

// ---------------------------------------------------------------------------
// K0: zero the BN stats accumulators (ws is poisoned 0xAA before every call)
__global__ void zero_stats_kernel(float* s0, float* s1) {
    int t = threadIdx.x;
    if (t < 2 * O0) s0[t] = 0.f;
    if (t < 2 * O1) s1[t] = 0.f;
}

// ---------------------------------------------------------------------------
// K1: f32 -> bf16 batched transpose  in[b][R][C] (f32) -> out[b][C][R] (bf16)
__global__ __launch_bounds__(256) void transpose_f32_bf16(const float* __restrict__ in,
                                                          u16* __restrict__ out,
                                                          int R, int C) {
    __shared__ float tile[32][33];
    int b  = blockIdx.z;
    int c0 = blockIdx.x * 32;
    int r0 = blockIdx.y * 32;
    const float* pin = in  + (size_t)b * R * C;
    u16*        pout = out + (size_t)b * R * C;
    int tx = threadIdx.x, ty = threadIdx.y;   // block (32,8)
#pragma unroll
    for (int j = 0; j < 4; ++j) {
        int r = ty + j * 8;
        tile[r][tx] = pin[(size_t)(r0 + r) * C + (c0 + tx)];
    }
    __syncthreads();
#pragma unroll
    for (int j = 0; j < 4; ++j) {
        int c = ty + j * 8;
        pout[(size_t)(c0 + c) * R + (r0 + tx)] = f2bf(tile[tx][c]);
    }
}

// ---------------------------------------------------------------------------
// elementwise f32 -> bf16 cast (weights)
__global__ __launch_bounds__(256) void cast_f32_bf16(const float* __restrict__ in,
                                                     u16* __restrict__ out, int n) {
    int i = blockIdx.x * 256 + threadIdx.x;
    if (i < n) out[i] = f2bf(in[i]);
}

// ---------------------------------------------------------------------------
// K2: 3-NN + combined (distance * normal) interpolation weights. f32 inputs.
// 8 threads per query; lane j scans pts[s*8+j] (stride-8 = conflict-free,
// broadcast across the 8 query-groups in a wave), then 3-step shfl_xor merge
// of sorted top-3 triples with lexicographic (d, idx) tie-break (= top_k
// stable-tie semantics). Distance replicates the reference order
// (qq + pp) - 2*qp with fp contract off (numpy tie fidelity).
__global__ __launch_bounds__(256) void three_nn_kernel(const float* __restrict__ xyz1,
                                                       const float* __restrict__ xyz2,
                                                       const float* __restrict__ norm1,
                                                       const float* __restrict__ norm2,
                                                       int* __restrict__ idxOut,
                                                       float* __restrict__ wOut) {
#pragma clang fp contract(off)
    __shared__ float4 pts[MM];
    int b    = blockIdx.x >> 8;          // 256 blocks of 32 queries per batch
    int nblk = blockIdx.x & 255;
    int t    = threadIdx.x;
    int j    = t & 7;                    // lane within the 8-thread query group

    const float* x2 = xyz2 + (size_t)b * 3 * MM;
    for (int i = t; i < MM; i += 256) {
        float px = x2[i];
        float py = x2[MM + i];
        float pz = x2[2 * MM + i];
        float pp = (px * px + py * py) + pz * pz;
        pts[i] = make_float4(px, py, pz, pp);
    }
    __syncthreads();

    int n = nblk * 32 + (t >> 3);
    const float* x1 = xyz1 + (size_t)b * 3 * NN;
    float qx = x1[n], qy = x1[NN + n], qz = x1[2 * NN + n];
    float qq = (qx * qx + qy * qy) + qz * qz;

    float d0 = 3.4e38f, d1 = 3.4e38f, d2v = 3.4e38f;
    int   i0 = 0, i1 = 0, i2 = 0;
#pragma unroll 8
    for (int s = 0; s < MM / 8; ++s) {
        int m = s * 8 + j;               // ascending per thread -> stable ties
        float4 P = pts[m];
        float qp = (qx * P.x + qy * P.y) + qz * P.z;
        float d  = (qq + P.w) - 2.0f * qp;
        if (d < d2v) {
            if (d < d1) {
                if (d < d0) { d2v = d1; i2 = i1; d1 = d0; i1 = i0; d0 = d; i0 = m; }
                else        { d2v = d1; i2 = i1; d1 = d;  i1 = m; }
            } else          { d2v = d;  i2 = m; }
        }
    }

    // merge sorted triples across the 8 lanes of the group (lexicographic tie-break)
#pragma unroll
    for (int k = 1; k <= 4; k <<= 1) {
        float e0 = __shfl_xor(d0, k, 64), e1 = __shfl_xor(d1, k, 64), e2 = __shfl_xor(d2v, k, 64);
        int   f0 = __shfl_xor(i0, k, 64), f1 = __shfl_xor(i1, k, 64), f2 = __shfl_xor(i2, k, 64);
        float ed[3] = {e0, e1, e2}; int ef[3] = {f0, f1, f2};
#pragma unroll
        for (int e = 0; e < 3; ++e) {
            float dd = ed[e]; int ff = ef[e];
            bool b2 = (dd < d2v) || (dd == d2v && ff < i2);
            if (b2) {
                bool b1 = (dd < d1) || (dd == d1 && ff < i1);
                if (b1) {
                    d2v = d1; i2 = i1;
                    bool b0 = (dd < d0) || (dd == d0 && ff < i0);
                    if (b0) { d1 = d0; i1 = i0; d0 = dd; i0 = ff; }
                    else    { d1 = dd; i1 = ff; }
                } else { d2v = dd; i2 = ff; }
            }
        }
    }

    if (j == 0) {
        // distance weights
        float s0 = sqrtf(fmaxf(d0, 1e-20f));
        float s1 = sqrtf(fmaxf(d1, 1e-20f));
        float s2 = sqrtf(fmaxf(d2v, 1e-20f));
        float r0 = 1.0f / fmaxf(s0, 1e-10f);
        float r1 = 1.0f / fmaxf(s1, 1e-10f);
        float r2 = 1.0f / fmaxf(s2, 1e-10f);
        float rs = (r0 + r1) + r2;
        float w0 = r0 / rs, w1 = r1 / rs, w2 = r2 / rs;

        // normal-space weights
        const float* nm1 = norm1 + (size_t)b * 3 * NN;
        const float* nm2 = norm2 + (size_t)b * 3 * MM;
        float ax = nm1[n], ay = nm1[NN + n], az = nm1[2 * NN + n];
        float nd[3]; int ii[3] = {i0, i1, i2};
#pragma unroll
        for (int k = 0; k < 3; ++k) {
            int ik = ii[k];
            float dx = ax - nm2[ik];
            float dy = ay - nm2[MM + ik];
            float dz = az - nm2[2 * MM + ik];
            nd[k] = sqrtf((dx * dx + dy * dy) + dz * dz);
        }
        float m0 = 1.0f / fmaxf(nd[0], 1e-10f);
        float m1 = 1.0f / fmaxf(nd[1], 1e-10f);
        float m2 = 1.0f / fmaxf(nd[2], 1e-10f);
        float ms = (m0 + m1) + m2;

        int col = b * NN + n;
        idxOut[col * 3 + 0] = i0;
        idxOut[col * 3 + 1] = i1;
        idxOut[col * 3 + 2] = i2;
        wOut[col * 3 + 0] = w0 * (m0 / ms);
        wOut[col * 3 + 1] = w1 * (m1 / ms);
        wOut[col * 3 + 2] = w2 * (m2 / ms);
    }
}

// ---------------------------------------------------------------------------
// K3: build x^T[col][k] (bf16, K-contiguous): k<256 = interpolated points2,
// k>=256 = copied points1 channels. 16 columns per 256-thread block.
__global__ __launch_bounds__(256) void build_xT_kernel(const int* __restrict__ idx,
                                                       const float* __restrict__ w,
                                                       const u16* __restrict__ p2T,
                                                       const u16* __restrict__ p1T,
                                                       u16* __restrict__ xT) {
    int t = threadIdx.x;
    int col0 = blockIdx.x * 16;
    for (int i = 0; i < 16; ++i) {
        int col = col0 + i;
        int b = col >> 13;          // col / 8192
        int n = col & (NN - 1);
        int i0 = idx[col * 3 + 0], i1 = idx[col * 3 + 1], i2 = idx[col * 3 + 2];
        float w0 = w[col * 3 + 0], w1 = w[col * 3 + 1], w2 = w[col * 3 + 2];
        const u16* base = p2T + (size_t)b * MM * C2;
        float v = w0 * bf2f(base[(size_t)i0 * C2 + t])
                + w1 * bf2f(base[(size_t)i1 * C2 + t])
                + w2 * bf2f(base[(size_t)i2 * C2 + t]);
        xT[(size_t)col * CH0 + t] = f2bf(v);
        if (t < C1) {
            xT[(size_t)col * CH0 + C2 + t] = p1T[((size_t)b * NN + n) * C1 + t];
        }
    }
}

// ---------------------------------------------------------------------------
// K4/K6: GEMM  C^T[col][m] = sum_k A[m][k] * Bt[col][k] + bias[m]
// 128x128 tile, BK=64, 256 threads (4 waves, 2x2 of 64x64), 16x16x32 bf16 MFMA.
// Also accumulates per-channel sum / sumsq (training-mode BN stats) via atomics.
// FUSE: apply z = relu(v*scaleB[k]+shiftB[k]) to B elements while staging.
template <int KDIM, int LDC, bool FUSE>
__global__ __launch_bounds__(256) void gemm_bt_kernel(const u16* __restrict__ A,
                                                      const u16* __restrict__ Bt,
                                                      u16* __restrict__ Ct,
                                                      const float* __restrict__ bias,
                                                      const float* __restrict__ scaleB,
                                                      const float* __restrict__ shiftB,
                                                      float* __restrict__ stats,
                                                      int Mtot) {
    __shared__ u16 As[128][72];   // [m][k]  pad 64->72 (+16B; row stride 144B = 9*16)
    __shared__ u16 Bs[128][72];   // [col][k]
    int t   = threadIdx.x;
    int mb0 = blockIdx.y * 128;
    int cb0 = blockIdx.x * 128;
    int l   = t & 63;
    int wv  = t >> 6;
    int lm  = l & 15;
    int q   = l >> 4;
    int wm0 = (wv & 1) * 64;
    int wn0 = (wv >> 1) * 64;

    f32x4 acc[4][4] = {};

    for (int k0 = 0; k0 < KDIM; k0 += 64) {
        // Stage full 128x64 bf16 tiles: 1024 chunks of 16B each, 256 threads x 4.
#pragma unroll
        for (int j = 0; j < 4; ++j) {
            int chunk = t + j * 256;      // 0..1023
            int row = chunk >> 3;         // 0..127
            int kc  = (chunk & 7) * 8;    // 0,8,...,56
            uint4 va = *(const uint4*)(A + (size_t)(mb0 + row) * KDIM + k0 + kc);
            *(uint4*)&As[row][kc] = va;
            uint4 vb = *(const uint4*)(Bt + (size_t)(cb0 + row) * KDIM + k0 + kc);
            if (FUSE) {
                union { uint4 v; u16 u[8]; } uu; uu.v = vb;
#pragma unroll
                for (int e = 0; e < 8; ++e) {
                    int kch = k0 + kc + e;
                    float f = bf2f(uu.u[e]);
                    f = fmaxf(f * scaleB[kch] + shiftB[kch], 0.f);
                    uu.u[e] = f2bf(f);
                }
                vb = uu.v;
            }
            *(uint4*)&Bs[row][kc] = vb;
        }
        __syncthreads();
#pragma unroll
        for (int ks = 0; ks < 2; ++ks) {
            short8 av[4], bv[4];
#pragma unroll
            for (int mi = 0; mi < 4; ++mi)
                av[mi] = *(const short8*)&As[wm0 + mi * 16 + lm][ks * 32 + q * 8];
#pragma unroll
            for (int ni = 0; ni < 4; ++ni)
                bv[ni] = *(const short8*)&Bs[wn0 + ni * 16 + lm][ks * 32 + q * 8];
#pragma unroll
            for (int mi = 0; mi < 4; ++mi)
#pragma unroll
                for (int ni = 0; ni < 4; ++ni)
                    acc[mi][ni] = __builtin_amdgcn_mfma_f32_16x16x32_bf16(
                        av[mi], bv[ni], acc[mi][ni], 0, 0, 0);
        }
        __syncthreads();
    }

    // Epilogue: bias add, bf16 store (C layout: col=lane&15, row=q*4+r), BN stats.
#pragma unroll
    for (int mi = 0; mi < 4; ++mi) {
        int mg = mb0 + wm0 + mi * 16 + q * 4;   // global row (channel), 4 consecutive
        float bv4[4];
#pragma unroll
        for (int r = 0; r < 4; ++r) bv4[r] = bias[mg + r];
        float s[4]  = {0.f, 0.f, 0.f, 0.f};
        float s2[4] = {0.f, 0.f, 0.f, 0.f};
#pragma unroll
        for (int ni = 0; ni < 4; ++ni) {
            int col = cb0 + wn0 + ni * 16 + lm;
            union { u16 u[4]; uint2 d; } pk;
#pragma unroll
            for (int r = 0; r < 4; ++r) {
                float v = acc[mi][ni][r] + bv4[r];
                s[r]  += v;
                s2[r] += v * v;
                pk.u[r] = f2bf(v);
            }
            *(uint2*)(Ct + (size_t)col * LDC + mg) = pk.d;
        }
#pragma unroll
        for (int r = 0; r < 4; ++r) {
            float a = s[r], b2 = s2[r];
#pragma unroll
            for (int off = 1; off < 16; off <<= 1) {
                a  += __shfl_xor(a, off, 64);
                b2 += __shfl_xor(b2, off, 64);
            }
            if (lm == 0) {
                atomicAdd(&stats[mg + r], a);
                atomicAdd(&stats[Mtot + mg + r], b2);
            }
        }
    }
}

// ---------------------------------------------------------------------------
// K5/K7: fold BN stats into scale/shift:  z = y*scale[c] + shift[c]
__global__ void bn_params_kernel(const float* __restrict__ stats,
                                 const float* __restrict__ g,
                                 const float* __restrict__ be,
                                 float* __restrict__ scale,
                                 float* __restrict__ shift,
                                 int Mtot, float invN) {
    int c = threadIdx.x;
    if (c < Mtot) {
        float mean = stats[c] * invN;
        float var  = fmaxf(stats[Mtot + c] * invN - mean * mean, 0.f);
        float inv  = rsqrtf(var + BN_EPS);
        float sc   = g[c] * inv;
        scale[c] = sc;
        shift[c] = be[c] - mean * sc;
    }
}

// ---------------------------------------------------------------------------
// K8: final BN+ReLU on y1^T[col][c] (bf16) and transpose to out[b][c][n] (f32).
__global__ __launch_bounds__(256) void finalize_kernel(const u16* __restrict__ y1T,
                                                       const float* __restrict__ scale,
                                                       const float* __restrict__ shift,
                                                       float* __restrict__ out) {
    __shared__ float tile[64][129];
    int t  = threadIdx.x;
    int b  = blockIdx.y;
    int n0 = blockIdx.x * 64;
#pragma unroll
    for (int it = 0; it < 32; ++it) {
        int flat = it * 256 + t;
        int cl = flat >> 7;          // local col 0..63
        int c  = flat & 127;
        int col = b * NN + n0 + cl;
        float v = bf2f(y1T[(size_t)col * O1 + c]);
        tile[cl][c] = fmaxf(v * scale[c] + shift[c], 0.f);
    }
    __syncthreads();
#pragma unroll
    for (int it = 0; it < 32; ++it) {
        int flat = it * 256 + t;
        int c  = flat >> 6;          // channel 0..127
        int nl = flat & 63;
        out[(size_t)b * O1 * NN + (size_t)c * NN + n0 + nl] = tile[nl][c];
    }
}

// ---------------------------------------------------------------------------
extern "C" void kernel_launch(void* const* d_in, const int* in_sizes, int n_in,
                              void* d_out, int out_size, void* d_ws, size_t ws_size,
                              hipStream_t stream) {
    (void)in_sizes; (void)n_in; (void)out_size; (void)ws_size;

    const float* xyz1    = (const float*)d_in[0];
    const float* xyz2    = (const float*)d_in[1];
    const float* norm1   = (const float*)d_in[2];
    const float* norm2   = (const float*)d_in[3];
    const float* points1 = (const float*)d_in[4];
    const float* points2 = (const float*)d_in[5];
    const float* W0f     = (const float*)d_in[6];
    const float* b0      = (const float*)d_in[7];
    const float* g0      = (const float*)d_in[8];
    const float* be0     = (const float*)d_in[9];
    const float* W1f     = (const float*)d_in[10];
    const float* b1      = (const float*)d_in[11];
    const float* g1      = (const float*)d_in[12];
    const float* be1     = (const float*)d_in[13];
    float* out = (float*)d_out;

    // workspace carve-up (all 256B-aligned)
    char* w8 = (char*)d_ws;
    size_t off = 0;
    auto carve = [&](size_t bytes) { void* p = w8 + off; off += (bytes + 255) & ~(size_t)255; return p; };
    int*   idxW   = (int*)  carve((size_t)NCOL * 3 * sizeof(int));     // 393 KB
    float* wW     = (float*)carve((size_t)NCOL * 3 * sizeof(float));   // 393 KB
    u16*   p2T    = (u16*)  carve((size_t)BB * MM * C2 * 2);           // 2 MB
    u16*   p1T    = (u16*)  carve((size_t)BB * NN * C1 * 2);           // 8 MB
    u16*   W0b    = (u16*)  carve((size_t)O0 * CH0 * 2);               // 192 KB
    u16*   W1b    = (u16*)  carve((size_t)O1 * O0 * 2);                // 64 KB
    u16*   xT     = (u16*)  carve((size_t)NCOL * CH0 * 2);             // 25 MB
    u16*   y0T    = (u16*)  carve((size_t)NCOL * O0 * 2);              // 16 MB
    u16*   y1T    = (u16*)  carve((size_t)NCOL * O1 * 2);              // 8 MB
    float* stats0 = (float*)carve(2 * O0 * sizeof(float));
    float* stats1 = (float*)carve(2 * O1 * sizeof(float));
    float* scale0 = (float*)carve(O0 * sizeof(float));
    float* shift0 = (float*)carve(O0 * sizeof(float));
    float* scale1 = (float*)carve(O1 * sizeof(float));
    float* shift1 = (float*)carve(O1 * sizeof(float));

    const float invN = 1.0f / (float)NCOL;

    zero_stats_kernel<<<1, 512, 0, stream>>>(stats0, stats1);

    // f32 -> bf16 transposes (feature tensors) and weight conversions.
    transpose_f32_bf16<<<dim3(MM / 32, C2 / 32, BB), dim3(32, 8), 0, stream>>>(points2, p2T, C2, MM);
    transpose_f32_bf16<<<dim3(NN / 32, C1 / 32, BB), dim3(32, 8), 0, stream>>>(points1, p1T, C1, NN);
    cast_f32_bf16<<<(O0 * CH0 + 255) / 256, 256, 0, stream>>>(W0f, W0b, O0 * CH0);
    cast_f32_bf16<<<(O1 * O0 + 255) / 256, 256, 0, stream>>>(W1f, W1b, O1 * O0);

    three_nn_kernel<<<BB * (NN / 32), 256, 0, stream>>>(xyz1, xyz2, norm1, norm2, idxW, wW);

    build_xT_kernel<<<NCOL / 16, 256, 0, stream>>>(idxW, wW, p2T, p1T, xT);

    gemm_bt_kernel<CH0, O0, false><<<dim3(NCOL / 128, O0 / 128), 256, 0, stream>>>(
        W0b, xT, y0T, b0, nullptr, nullptr, stats0, O0);
    bn_params_kernel<<<1, O0, 0, stream>>>(stats0, g0, be0, scale0, shift0, O0, invN);

    gemm_bt_kernel<O0, O1, true><<<dim3(NCOL / 128, O1 / 128), 256, 0, stream>>>(
        W1b, y0T, y1T, b1, scale0, shift0, stats1, O1);
    bn_params_kernel<<<1, O1, 0, stream>>>(stats1, g1, be1, scale1, shift1, O1, invN);

    finalize_kernel<<<dim3(NN / 64, BB), 256, 0, stream>>>(y1T, scale1, shift1, out);
}